// Round 1
// baseline (13627.139 us; speedup 1.0000x reference)
//
#include <hip/hip_runtime.h>
#include <hip/hip_bf16.h>
#include <stdint.h>

#define NRAYS   1048576
#define TITERS  4
#define NPTS    8
#define DIM     64
#define NLAYERS 2
#define INFV    1e9f

// Load element i of a "float-ish" tensor. fm==1 -> float32, fm==0 -> bf16.
__device__ __forceinline__ float ldf(const void* p, int i, int fm) {
    if (fm) return ((const float*)p)[i];
    unsigned int u = ((const unsigned short*)p)[i];
    return __uint_as_float(u << 16);
}

__global__ __launch_bounds__(256) void nbvh_kernel(
    const void* __restrict__ orig_p, const void* __restrict__ vec_p,
    const void* __restrict__ masks_p, const void* __restrict__ t1_p,
    const void* __restrict__ t2_p,   const void* __restrict__ mmin_p,
    const void* __restrict__ mmax_p, const void* __restrict__ W0_p,
    const void* __restrict__ b0_p,   const void* __restrict__ lng_p,
    const void* __restrict__ lnb_p,  const void* __restrict__ Ws_p,
    const void* __restrict__ bs_p,   const void* __restrict__ Wc_p,
    const void* __restrict__ bc_p,   const void* __restrict__ Wd_p,
    const void* __restrict__ bd_p,   void* __restrict__ out_p)
{
    __shared__ __align__(16) float sW0[24 * 64];
    __shared__ __align__(16) float sWs[2 * 64 * 64];
    __shared__ __align__(16) float sB0[64];
    __shared__ __align__(16) float sWc[64];
    __shared__ __align__(16) float sWd[64];
    __shared__ __align__(16) float sG[128];
    __shared__ __align__(16) float sBt[128];
    __shared__ __align__(16) float sBs[128];
    __shared__ float sScal[8];   // mn[3], 1/scale[3], bc, bd
    __shared__ int   sMode[2];   // fm (0=bf16,1=f32), mask elem size {1,2,4}

    const int tid = threadIdx.x;

    // ---- dtype sniffing (deterministic: inputs restored pristine each call) ----
    if (tid == 0) {
        uint32_t w0 = ((const uint32_t*)mmin_p)[0];        // -1.0: bf16 pair 0xBF80BF80 / f32 0xBF800000
        int fm = ((w0 & 0xFFFFu) == 0u) ? 1 : 0;
        const uint32_t* mw = (const uint32_t*)masks_p;
        bool sawBf = false, allBin = true, sawF32 = false;
        for (int i = 0; i < 64; ++i) {
            uint32_t w = mw[i];
            uint32_t lo = w & 0xFFFFu, hi = w >> 16;
            if (lo == 0x3F80u && (hi == 0x3F80u || hi == 0u)) sawBf = true;  // bf16 1.0 in even slot
            if (w == 0x3F800000u) sawF32 = true;                              // f32 1.0
            if (w > 1u) allBin = false;                                       // int32 0/1 words
        }
        int ms = sawBf ? 2 : (allBin ? 4 : (sawF32 ? 4 : 1));
        sMode[0] = fm; sMode[1] = ms;
    }
    __syncthreads();
    const int fm = sMode[0];
    const int ms = sMode[1];

    // ---- stage weights (converted to f32) into LDS ----
    for (int i = tid; i < 24 * 64;     i += 256) sW0[i] = ldf(W0_p, i, fm);
    for (int i = tid; i < 2 * 64 * 64; i += 256) sWs[i] = ldf(Ws_p, i, fm);
    if (tid < 64) {
        sB0[tid] = ldf(b0_p, tid, fm);
        sWc[tid] = ldf(Wc_p, tid, fm);
        sWd[tid] = ldf(Wd_p, tid, fm);
    } else if (tid < 192) {
        int i = tid - 64;
        sG [i] = ldf(lng_p, i, fm);
        sBt[i] = ldf(lnb_p, i, fm);
        sBs[i] = ldf(bs_p,  i, fm);
    } else if (tid == 192) {
        for (int c = 0; c < 3; ++c) {
            float mn = ldf(mmin_p, c, fm), mx = ldf(mmax_p, c, fm);
            float ext = mx - mn;
            sScal[c]     = mn - 0.5f * ext;     // min_infl
            sScal[3 + c] = 1.0f / (2.0f * ext); // 1/scale
        }
        sScal[6] = ldf(bc_p, 0, fm);
        sScal[7] = ldf(bd_p, 0, fm);
    }
    __syncthreads();

    const int ray = blockIdx.x * 256 + tid;
    float ox = ldf(orig_p, 3 * ray + 0, fm);
    float oy = ldf(orig_p, 3 * ray + 1, fm);
    float oz = ldf(orig_p, 3 * ray + 2, fm);
    float vx = ldf(vec_p,  3 * ray + 0, fm);
    float vy = ldf(vec_p,  3 * ray + 1, fm);
    float vz = ldf(vec_p,  3 * ray + 2, fm);
    const float mnx = sScal[0], mny = sScal[1], mnz = sScal[2];
    const float isx = sScal[3], isy = sScal[4], isz = sScal[5];
    const float bcv = sScal[6], bdv = sScal[7];

    float dist = INFV;

#pragma unroll 1
    for (int it = 0; it < TITERS; ++it) {
        const int gi = it * NRAYS + ray;
        bool mk;
        if      (ms == 1) mk = ((const uint8_t*) masks_p)[gi] != 0;
        else if (ms == 2) mk = ((const uint16_t*)masks_p)[gi] != 0;
        else              mk = ((const uint32_t*)masks_p)[gi] != 0;
        const float ct1 = ldf(t1_p, gi, fm);
        const float ct2 = ldf(t2_p, gi, fm);
        const float dt = ct2 - ct1;
        const float ax = fmaf(vx, ct1, ox), ay = fmaf(vy, ct1, oy), az = fmaf(vz, ct1, oz);
        const float bx = vx * dt, by = vy * dt, bz = vz * dt;

        // ---- layer 0: x[24] @ W0[24x64] + b0 ----
        float acc[DIM];
#pragma unroll
        for (int j = 0; j < 16; ++j) {
            float4 b = ((const float4*)sB0)[j];
            acc[4*j] = b.x; acc[4*j+1] = b.y; acc[4*j+2] = b.z; acc[4*j+3] = b.w;
        }
#pragma unroll
        for (int p = 0; p < NPTS; ++p) {
            const float tp = (float)p * (1.0f / 7.0f);
            const float x0 = (fmaf(bx, tp, ax) - mnx) * isx;
            const float x1 = (fmaf(by, tp, ay) - mny) * isy;
            const float x2 = (fmaf(bz, tp, az) - mnz) * isz;
            const float4* r0 = (const float4*)(sW0 + (3 * p + 0) * 64);
            const float4* r1 = (const float4*)(sW0 + (3 * p + 1) * 64);
            const float4* r2 = (const float4*)(sW0 + (3 * p + 2) * 64);
#pragma unroll
            for (int j = 0; j < 16; ++j) {
                float4 w0 = r0[j], w1 = r1[j], w2 = r2[j];
                acc[4*j+0] = fmaf(x2, w2.x, fmaf(x1, w1.x, fmaf(x0, w0.x, acc[4*j+0])));
                acc[4*j+1] = fmaf(x2, w2.y, fmaf(x1, w1.y, fmaf(x0, w0.y, acc[4*j+1])));
                acc[4*j+2] = fmaf(x2, w2.z, fmaf(x1, w1.z, fmaf(x0, w0.z, acc[4*j+2])));
                acc[4*j+3] = fmaf(x2, w2.w, fmaf(x1, w1.w, fmaf(x0, w0.w, acc[4*j+3])));
            }
        }

        // ---- 2 x (relu -> layernorm -> @Ws + bs) ----
#pragma unroll 1
        for (int li = 0; li < NLAYERS; ++li) {
            float s = 0.f;
#pragma unroll
            for (int j = 0; j < DIM; ++j) { acc[j] = fmaxf(acc[j], 0.f); s += acc[j]; }
            const float mu = s * (1.0f / DIM);
            float v = 0.f;
#pragma unroll
            for (int j = 0; j < DIM; ++j) { float d = acc[j] - mu; v = fmaf(d, d, v); }
            const float rs = rsqrtf(fmaf(v, 1.0f / DIM, 1e-5f));
            const float* g = sG  + li * 64;
            const float* b = sBt + li * 64;
#pragma unroll
            for (int j = 0; j < DIM; ++j) acc[j] = fmaf((acc[j] - mu) * rs, g[j], b[j]);

            float z[DIM];
            const float4* bsrow = (const float4*)(sBs + li * 64);
#pragma unroll
            for (int j = 0; j < 16; ++j) {
                float4 b4 = bsrow[j];
                z[4*j] = b4.x; z[4*j+1] = b4.y; z[4*j+2] = b4.z; z[4*j+3] = b4.w;
            }
            const float* wbase = sWs + li * 64 * 64;
#pragma unroll
            for (int k = 0; k < DIM; ++k) {
                const float yk = acc[k];
                const float4* wr = (const float4*)(wbase + k * 64);
#pragma unroll
                for (int j = 0; j < 16; ++j) {
                    float4 w = wr[j];
                    z[4*j+0] = fmaf(yk, w.x, z[4*j+0]);
                    z[4*j+1] = fmaf(yk, w.y, z[4*j+1]);
                    z[4*j+2] = fmaf(yk, w.z, z[4*j+2]);
                    z[4*j+3] = fmaf(yk, w.w, z[4*j+3]);
                }
            }
#pragma unroll
            for (int j = 0; j < DIM; ++j) acc[j] = z[j];
        }

        // ---- heads ----
        float cls = bcv, dvv = bdv;
#pragma unroll
        for (int j = 0; j < DIM; ++j) {
            float yj = fmaxf(acc[j], 0.f);
            cls = fmaf(yj, sWc[j], cls);
            dvv = fmaf(yj, sWd[j], dvv);
        }
        const float dval = dvv + ct1;
        if (mk && cls > 0.f && dval < dist) dist = dval;
    }

    if (dist == INFV) dist = 0.f;
    const float hit = (dist > 0.f) ? 1.0f : 0.0f;
    if (fm) {
        ((float*)out_p)[ray]         = hit;
        ((float*)out_p)[NRAYS + ray] = dist;
    } else {
        __hip_bfloat16* o = (__hip_bfloat16*)out_p;
        o[ray]         = __float2bfloat16(hit);
        o[NRAYS + ray] = __float2bfloat16(dist);
    }
}

extern "C" void kernel_launch(void* const* d_in, const int* in_sizes, int n_in,
                              void* d_out, int out_size, void* d_ws, size_t ws_size,
                              hipStream_t stream) {
    (void)in_sizes; (void)n_in; (void)d_ws; (void)ws_size; (void)out_size;
    nbvh_kernel<<<NRAYS / 256, 256, 0, stream>>>(
        d_in[0], d_in[1], d_in[2],  /* skip d_in[3] bbox_idxs (unused) */
        d_in[4], d_in[5], d_in[6], d_in[7],
        d_in[8], d_in[9], d_in[10], d_in[11],
        d_in[12], d_in[13], d_in[14], d_in[15],
        d_in[16], d_in[17], d_out);
}

// Round 2
// 1610.700 us; speedup vs baseline: 8.4604x; 8.4604x over previous
//
#include <hip/hip_runtime.h>
#include <hip/hip_bf16.h>
#include <stdint.h>

#define NRAYS   1048576
#define TITERS  4
#define NPTS    8
#define DIM     64
#define NLAYERS 2
#define INFV    1e9f

// Load element i of a "float-ish" tensor. fm==1 -> float32, fm==0 -> bf16.
__device__ __forceinline__ float ldf(const void* p, int i, int fm) {
    if (fm) return ((const float*)p)[i];
    unsigned int u = ((const unsigned short*)p)[i];
    return __uint_as_float(u << 16);
}

// Lane pair {2p,2p+1} handles rays {2p,2p+1}; lane owns dim-half h = tid&1
// (j in [h*32, h*32+32)). Per-lane register arrays are 2 rays x 32 dims.
__global__ __launch_bounds__(256) void nbvh_kernel(
    const void* __restrict__ orig_p, const void* __restrict__ vec_p,
    const void* __restrict__ masks_p, const void* __restrict__ t1_p,
    const void* __restrict__ t2_p,   const void* __restrict__ mmin_p,
    const void* __restrict__ mmax_p, const void* __restrict__ W0_p,
    const void* __restrict__ b0_p,   const void* __restrict__ lng_p,
    const void* __restrict__ lnb_p,  const void* __restrict__ Ws_p,
    const void* __restrict__ bs_p,   const void* __restrict__ Wc_p,
    const void* __restrict__ bc_p,   const void* __restrict__ Wd_p,
    const void* __restrict__ bd_p,   void* __restrict__ out_p)
{
    __shared__ __align__(16) float sW0[24 * 64];
    __shared__ __align__(16) float sWs[2 * 64 * 64];
    __shared__ __align__(16) float sB0[64];
    __shared__ __align__(16) float sWc[64];
    __shared__ __align__(16) float sWd[64];
    __shared__ __align__(16) float sG[128];
    __shared__ __align__(16) float sBt[128];
    __shared__ __align__(16) float sBs[128];
    __shared__ float sScal[8];
    __shared__ int   sMode[2];

    const int tid = threadIdx.x;

    // ---- dtype sniffing (deterministic; validated in round 1) ----
    if (tid == 0) {
        uint32_t w0 = ((const uint32_t*)mmin_p)[0];
        int fm = ((w0 & 0xFFFFu) == 0u) ? 1 : 0;
        const uint32_t* mw = (const uint32_t*)masks_p;
        bool sawBf = false, allBin = true, sawF32 = false;
        for (int i = 0; i < 64; ++i) {
            uint32_t w = mw[i];
            uint32_t lo = w & 0xFFFFu, hi = w >> 16;
            if (lo == 0x3F80u && (hi == 0x3F80u || hi == 0u)) sawBf = true;
            if (w == 0x3F800000u) sawF32 = true;
            if (w > 1u) allBin = false;
        }
        int ms = sawBf ? 2 : (allBin ? 4 : (sawF32 ? 4 : 1));
        sMode[0] = fm; sMode[1] = ms;
    }
    __syncthreads();
    const int fm = sMode[0];
    const int ms = sMode[1];

    // ---- stage weights (f32) into LDS ----
    for (int i = tid; i < 24 * 64;     i += 256) sW0[i] = ldf(W0_p, i, fm);
    for (int i = tid; i < 2 * 64 * 64; i += 256) sWs[i] = ldf(Ws_p, i, fm);
    if (tid < 64) {
        sB0[tid] = ldf(b0_p, tid, fm);
        sWc[tid] = ldf(Wc_p, tid, fm);
        sWd[tid] = ldf(Wd_p, tid, fm);
    } else if (tid < 192) {
        int i = tid - 64;
        sG [i] = ldf(lng_p, i, fm);
        sBt[i] = ldf(lnb_p, i, fm);
        sBs[i] = ldf(bs_p,  i, fm);
    } else if (tid == 192) {
        for (int c = 0; c < 3; ++c) {
            float mn = ldf(mmin_p, c, fm), mx = ldf(mmax_p, c, fm);
            float ext = mx - mn;
            sScal[c]     = mn - 0.5f * ext;
            sScal[3 + c] = 1.0f / (2.0f * ext);
        }
        sScal[6] = ldf(bc_p, 0, fm);
        sScal[7] = ldf(bd_p, 0, fm);
    }
    __syncthreads();

    const int h = tid & 1;                       // dim half
    const int ray0 = blockIdx.x * 256 + (tid & ~1);
    const int ray1 = ray0 + 1;

    const float mnx = sScal[0], mny = sScal[1], mnz = sScal[2];
    const float isx = sScal[3], isy = sScal[4], isz = sScal[5];
    const float bcv = sScal[6], bdv = sScal[7];

    const float ox0 = ldf(orig_p, 3*ray0+0, fm), oy0 = ldf(orig_p, 3*ray0+1, fm), oz0 = ldf(orig_p, 3*ray0+2, fm);
    const float vx0 = ldf(vec_p,  3*ray0+0, fm), vy0 = ldf(vec_p,  3*ray0+1, fm), vz0 = ldf(vec_p,  3*ray0+2, fm);
    const float ox1 = ldf(orig_p, 3*ray1+0, fm), oy1 = ldf(orig_p, 3*ray1+1, fm), oz1 = ldf(orig_p, 3*ray1+2, fm);
    const float vx1 = ldf(vec_p,  3*ray1+0, fm), vy1 = ldf(vec_p,  3*ray1+1, fm), vz1 = ldf(vec_p,  3*ray1+2, fm);

    float dist0 = INFV, dist1 = INFV;

#pragma unroll 1
    for (int it = 0; it < TITERS; ++it) {
        const int gi0 = it * NRAYS + ray0;
        const int gi1 = gi0 + 1;
        bool mk0, mk1;
        if      (ms == 1) { mk0 = ((const uint8_t*) masks_p)[gi0] != 0; mk1 = ((const uint8_t*) masks_p)[gi1] != 0; }
        else if (ms == 2) { mk0 = ((const uint16_t*)masks_p)[gi0] != 0; mk1 = ((const uint16_t*)masks_p)[gi1] != 0; }
        else              { mk0 = ((const uint32_t*)masks_p)[gi0] != 0; mk1 = ((const uint32_t*)masks_p)[gi1] != 0; }
        const float ct1_0 = ldf(t1_p, gi0, fm), ct2_0 = ldf(t2_p, gi0, fm);
        const float ct1_1 = ldf(t1_p, gi1, fm), ct2_1 = ldf(t2_p, gi1, fm);
        const float dt0 = ct2_0 - ct1_0, dt1 = ct2_1 - ct1_1;
        const float ax0 = fmaf(vx0, ct1_0, ox0), ay0 = fmaf(vy0, ct1_0, oy0), az0 = fmaf(vz0, ct1_0, oz0);
        const float ax1 = fmaf(vx1, ct1_1, ox1), ay1 = fmaf(vy1, ct1_1, oy1), az1 = fmaf(vz1, ct1_1, oz1);
        const float bx0 = vx0 * dt0, by0 = vy0 * dt0, bz0 = vz0 * dt0;
        const float bx1 = vx1 * dt1, by1 = vy1 * dt1, bz1 = vz1 * dt1;

        float z0[32], z1[32];
        // ---- layer 0: z = b0 + x @ W0 (my 32-col half, both rays) ----
        {
            const float4* b04 = (const float4*)(sB0 + h * 32);
#pragma unroll
            for (int q = 0; q < 8; ++q) {
                float4 b4 = b04[q];
                z0[4*q+0] = b4.x; z0[4*q+1] = b4.y; z0[4*q+2] = b4.z; z0[4*q+3] = b4.w;
                z1[4*q+0] = b4.x; z1[4*q+1] = b4.y; z1[4*q+2] = b4.z; z1[4*q+3] = b4.w;
            }
#pragma unroll 2
            for (int p = 0; p < NPTS; ++p) {
                const float tp = (float)p * (1.0f / 7.0f);
                float xr0[3], xr1[3];
                xr0[0] = (fmaf(bx0, tp, ax0) - mnx) * isx;
                xr0[1] = (fmaf(by0, tp, ay0) - mny) * isy;
                xr0[2] = (fmaf(bz0, tp, az0) - mnz) * isz;
                xr1[0] = (fmaf(bx1, tp, ax1) - mnx) * isx;
                xr1[1] = (fmaf(by1, tp, ay1) - mny) * isy;
                xr1[2] = (fmaf(bz1, tp, az1) - mnz) * isz;
#pragma unroll
                for (int c = 0; c < 3; ++c) {
                    const float4* wr = (const float4*)(sW0 + (3*p + c) * 64 + h * 32);
                    const float xc0 = xr0[c], xc1 = xr1[c];
#pragma unroll
                    for (int q = 0; q < 8; ++q) {
                        float4 w = wr[q];
                        z0[4*q+0] = fmaf(xc0, w.x, z0[4*q+0]);
                        z0[4*q+1] = fmaf(xc0, w.y, z0[4*q+1]);
                        z0[4*q+2] = fmaf(xc0, w.z, z0[4*q+2]);
                        z0[4*q+3] = fmaf(xc0, w.w, z0[4*q+3]);
                        z1[4*q+0] = fmaf(xc1, w.x, z1[4*q+0]);
                        z1[4*q+1] = fmaf(xc1, w.y, z1[4*q+1]);
                        z1[4*q+2] = fmaf(xc1, w.z, z1[4*q+2]);
                        z1[4*q+3] = fmaf(xc1, w.w, z1[4*q+3]);
                    }
                }
            }
        }

        // ---- 2 x (relu -> LN -> @Ws + bs) ----
        float y0[32], y1[32];
#pragma unroll 1
        for (int li = 0; li < NLAYERS; ++li) {
            float s0 = 0.f, s1 = 0.f;
#pragma unroll
            for (int j = 0; j < 32; ++j) {
                z0[j] = fmaxf(z0[j], 0.f); z1[j] = fmaxf(z1[j], 0.f);
                s0 += z0[j]; s1 += z1[j];
            }
            s0 += __shfl_xor(s0, 1); s1 += __shfl_xor(s1, 1);
            const float mu0 = s0 * (1.0f / DIM), mu1 = s1 * (1.0f / DIM);
            float v0 = 0.f, v1 = 0.f;
#pragma unroll
            for (int j = 0; j < 32; ++j) {
                float d0 = z0[j] - mu0, d1 = z1[j] - mu1;
                v0 = fmaf(d0, d0, v0); v1 = fmaf(d1, d1, v1);
            }
            v0 += __shfl_xor(v0, 1); v1 += __shfl_xor(v1, 1);
            const float rs0 = rsqrtf(fmaf(v0, 1.0f / DIM, 1e-5f));
            const float rs1 = rsqrtf(fmaf(v1, 1.0f / DIM, 1e-5f));
            const float4* g4 = (const float4*)(sG  + li * 64 + h * 32);
            const float4* t4 = (const float4*)(sBt + li * 64 + h * 32);
#pragma unroll
            for (int q = 0; q < 8; ++q) {
                float4 gq = g4[q], bq = t4[q];
                y0[4*q+0] = fmaf((z0[4*q+0]-mu0)*rs0, gq.x, bq.x);
                y0[4*q+1] = fmaf((z0[4*q+1]-mu0)*rs0, gq.y, bq.y);
                y0[4*q+2] = fmaf((z0[4*q+2]-mu0)*rs0, gq.z, bq.z);
                y0[4*q+3] = fmaf((z0[4*q+3]-mu0)*rs0, gq.w, bq.w);
                y1[4*q+0] = fmaf((z1[4*q+0]-mu1)*rs1, gq.x, bq.x);
                y1[4*q+1] = fmaf((z1[4*q+1]-mu1)*rs1, gq.y, bq.y);
                y1[4*q+2] = fmaf((z1[4*q+2]-mu1)*rs1, gq.z, bq.z);
                y1[4*q+3] = fmaf((z1[4*q+3]-mu1)*rs1, gq.w, bq.w);
            }
            const float4* bs4 = (const float4*)(sBs + li * 64 + h * 32);
#pragma unroll
            for (int q = 0; q < 8; ++q) {
                float4 b4 = bs4[q];
                z0[4*q+0] = b4.x; z0[4*q+1] = b4.y; z0[4*q+2] = b4.z; z0[4*q+3] = b4.w;
                z1[4*q+0] = b4.x; z1[4*q+1] = b4.y; z1[4*q+2] = b4.z; z1[4*q+3] = b4.w;
            }
            const float* wbase = sWs + li * 4096;
            const int ownk = h * 32;
            const int othk = 32 - ownk;
#pragma unroll
            for (int i = 0; i < 32; ++i) {
                const float a0 = y0[i], a1 = y1[i];
                const float p0 = __shfl_xor(a0, 1);   // partner's act for k = othk+i
                const float p1 = __shfl_xor(a1, 1);
                const float4* wO = (const float4*)(wbase + (ownk + i) * 64 + h * 32);
                const float4* wT = (const float4*)(wbase + (othk + i) * 64 + h * 32);
#pragma unroll
                for (int q = 0; q < 8; ++q) {
                    float4 w1 = wO[q], w2 = wT[q];
                    z0[4*q+0] = fmaf(a0, w1.x, fmaf(p0, w2.x, z0[4*q+0]));
                    z0[4*q+1] = fmaf(a0, w1.y, fmaf(p0, w2.y, z0[4*q+1]));
                    z0[4*q+2] = fmaf(a0, w1.z, fmaf(p0, w2.z, z0[4*q+2]));
                    z0[4*q+3] = fmaf(a0, w1.w, fmaf(p0, w2.w, z0[4*q+3]));
                    z1[4*q+0] = fmaf(a1, w1.x, fmaf(p1, w2.x, z1[4*q+0]));
                    z1[4*q+1] = fmaf(a1, w1.y, fmaf(p1, w2.y, z1[4*q+1]));
                    z1[4*q+2] = fmaf(a1, w1.z, fmaf(p1, w2.z, z1[4*q+2]));
                    z1[4*q+3] = fmaf(a1, w1.w, fmaf(p1, w2.w, z1[4*q+3]));
                }
            }
        }

        // ---- heads: relu(z) . Wc / Wd ----
        float c0 = 0.f, c1 = 0.f, d0 = 0.f, d1 = 0.f;
        {
            const float4* wc4 = (const float4*)(sWc + h * 32);
            const float4* wd4 = (const float4*)(sWd + h * 32);
#pragma unroll
            for (int q = 0; q < 8; ++q) {
                float4 wc = wc4[q], wd = wd4[q];
                float r00 = fmaxf(z0[4*q+0], 0.f), r01 = fmaxf(z0[4*q+1], 0.f);
                float r02 = fmaxf(z0[4*q+2], 0.f), r03 = fmaxf(z0[4*q+3], 0.f);
                float r10 = fmaxf(z1[4*q+0], 0.f), r11 = fmaxf(z1[4*q+1], 0.f);
                float r12 = fmaxf(z1[4*q+2], 0.f), r13 = fmaxf(z1[4*q+3], 0.f);
                c0 = fmaf(r03, wc.w, fmaf(r02, wc.z, fmaf(r01, wc.y, fmaf(r00, wc.x, c0))));
                d0 = fmaf(r03, wd.w, fmaf(r02, wd.z, fmaf(r01, wd.y, fmaf(r00, wd.x, d0))));
                c1 = fmaf(r13, wc.w, fmaf(r12, wc.z, fmaf(r11, wc.y, fmaf(r10, wc.x, c1))));
                d1 = fmaf(r13, wd.w, fmaf(r12, wd.z, fmaf(r11, wd.y, fmaf(r10, wd.x, d1))));
            }
        }
        c0 += __shfl_xor(c0, 1); c1 += __shfl_xor(c1, 1);
        d0 += __shfl_xor(d0, 1); d1 += __shfl_xor(d1, 1);
        const float cls0 = c0 + bcv, cls1 = c1 + bcv;
        const float dv0 = d0 + bdv + ct1_0;
        const float dv1 = d1 + bdv + ct1_1;
        if (mk0 && cls0 > 0.f && dv0 < dist0) dist0 = dv0;
        if (mk1 && cls1 > 0.f && dv1 < dist1) dist1 = dv1;
    }

    // lane writes ray = ray0 + h (both lanes hold both rays' results)
    float dmine = h ? dist1 : dist0;
    if (dmine == INFV) dmine = 0.f;
    const float hit = (dmine > 0.f) ? 1.0f : 0.0f;
    const int wray = ray0 + h;
    if (fm) {
        ((float*)out_p)[wray]         = hit;
        ((float*)out_p)[NRAYS + wray] = dmine;
    } else {
        __hip_bfloat16* o = (__hip_bfloat16*)out_p;
        o[wray]         = __float2bfloat16(hit);
        o[NRAYS + wray] = __float2bfloat16(dmine);
    }
}

extern "C" void kernel_launch(void* const* d_in, const int* in_sizes, int n_in,
                              void* d_out, int out_size, void* d_ws, size_t ws_size,
                              hipStream_t stream) {
    (void)in_sizes; (void)n_in; (void)d_ws; (void)ws_size; (void)out_size;
    nbvh_kernel<<<NRAYS / 256, 256, 0, stream>>>(
        d_in[0], d_in[1], d_in[2],
        d_in[4], d_in[5], d_in[6], d_in[7],
        d_in[8], d_in[9], d_in[10], d_in[11],
        d_in[12], d_in[13], d_in[14], d_in[15],
        d_in[16], d_in[17], d_out);
}

// Round 3
// 1147.735 us; speedup vs baseline: 11.8731x; 1.4034x over previous
//
#include <hip/hip_runtime.h>
#include <hip/hip_bf16.h>
#include <stdint.h>

#define NRAYS   1048576
#define TITERS  4
#define NPTS    8
#define DIM     64
#define NLAYERS 2
#define INFV    1e9f

// d_ws float-index layout (all f32 after conversion):
#define OFF_SCAL 0      // mnx,mny,mnz, isx,isy,isz, bc, bd
#define OFF_FLAG 8      // [8]=fm (int), [9]=ms (int)
#define OFF_W0   16     // 24*64
#define OFF_B0   1552   // 64
#define OFF_WSM  1616   // 2*64*64
#define OFF_BS   9808   // 2*64
#define OFF_G    9936   // 2*64
#define OFF_BT   10064  // 2*64
#define OFF_WC   10192  // 64
#define OFF_WD   10256  // 64
// total 10320 floats = 41280 bytes of d_ws

__device__ __forceinline__ float ldf(const void* p, int i, int fm) {
    if (fm) return ((const float*)p)[i];
    unsigned int u = ((const unsigned short*)p)[i];
    return __uint_as_float(u << 16);
}

// Prologue: sniff dtypes, convert all weights to f32 into d_ws. One block.
__global__ __launch_bounds__(256) void conv_k(
    const void* __restrict__ mmin, const void* __restrict__ mmax,
    const void* __restrict__ masks,
    const void* __restrict__ W0, const void* __restrict__ b0,
    const void* __restrict__ lng, const void* __restrict__ lnb,
    const void* __restrict__ Ws, const void* __restrict__ bs,
    const void* __restrict__ Wc, const void* __restrict__ bc,
    const void* __restrict__ Wd, const void* __restrict__ bd,
    float* __restrict__ ws)
{
    __shared__ int sfm;
    const int tid = threadIdx.x;
    if (tid == 0) {
        uint32_t w0 = ((const uint32_t*)mmin)[0];   // -1.0: bf16-pair vs f32
        int fm = ((w0 & 0xFFFFu) == 0u) ? 1 : 0;
        const uint32_t* mw = (const uint32_t*)masks;
        bool sawBf = false, allBin = true, sawF32 = false;
        for (int i = 0; i < 64; ++i) {
            uint32_t w = mw[i];
            uint32_t lo = w & 0xFFFFu, hi = w >> 16;
            if (lo == 0x3F80u && (hi == 0x3F80u || hi == 0u)) sawBf = true;
            if (w == 0x3F800000u) sawF32 = true;
            if (w > 1u) allBin = false;
        }
        int ms = sawBf ? 2 : (allBin ? 4 : (sawF32 ? 4 : 1));
        ((int*)ws)[OFF_FLAG]     = fm;
        ((int*)ws)[OFF_FLAG + 1] = ms;
        for (int c = 0; c < 3; ++c) {
            float mn = ldf(mmin, c, fm), mx = ldf(mmax, c, fm);
            float ext = mx - mn;
            ws[c]     = mn - 0.5f * ext;        // min_infl
            ws[3 + c] = 1.0f / (2.0f * ext);    // 1/scale
        }
        ws[6] = ldf(bc, 0, fm);
        ws[7] = ldf(bd, 0, fm);
        sfm = fm;
    }
    __syncthreads();
    const int fm = sfm;
    for (int i = tid; i < 1536; i += 256) ws[OFF_W0  + i] = ldf(W0,  i, fm);
    for (int i = tid; i < 64;   i += 256) ws[OFF_B0  + i] = ldf(b0,  i, fm);
    for (int i = tid; i < 8192; i += 256) ws[OFF_WSM + i] = ldf(Ws,  i, fm);
    for (int i = tid; i < 128;  i += 256) ws[OFF_BS  + i] = ldf(bs,  i, fm);
    for (int i = tid; i < 128;  i += 256) ws[OFF_G   + i] = ldf(lng, i, fm);
    for (int i = tid; i < 128;  i += 256) ws[OFF_BT  + i] = ldf(lnb, i, fm);
    for (int i = tid; i < 64;   i += 256) ws[OFF_WC  + i] = ldf(Wc,  i, fm);
    for (int i = tid; i < 64;   i += 256) ws[OFF_WD  + i] = ldf(Wd,  i, fm);
}

// Main: 1 ray per lane. Activations in VGPRs (constant-indexed only — all
// dim loops fully unrolled). Weights read with wave-uniform addresses from
// d_ws -> scalar s_load path; no LDS, no shuffles, no cross-lane anything.
__global__ __launch_bounds__(256) void nbvh_main(
    const void* __restrict__ orig_p, const void* __restrict__ vec_p,
    const void* __restrict__ masks_p, const void* __restrict__ t1_p,
    const void* __restrict__ t2_p, const float* __restrict__ ws,
    void* __restrict__ out_p)
{
    const int fm = ((const int*)ws)[OFF_FLAG];
    const int ms = ((const int*)ws)[OFF_FLAG + 1];
    const float mnx = ws[0], mny = ws[1], mnz = ws[2];
    const float isx = ws[3], isy = ws[4], isz = ws[5];
    const float bcv = ws[6], bdv = ws[7];

    const int ray = blockIdx.x * 256 + threadIdx.x;
    const float ox = ldf(orig_p, 3*ray+0, fm), oy = ldf(orig_p, 3*ray+1, fm), oz = ldf(orig_p, 3*ray+2, fm);
    const float vx = ldf(vec_p,  3*ray+0, fm), vy = ldf(vec_p,  3*ray+1, fm), vz = ldf(vec_p,  3*ray+2, fm);

    float dist = INFV;

#pragma unroll 1
    for (int it = 0; it < TITERS; ++it) {
        const int gi = it * NRAYS + ray;
        bool mk;
        if      (ms == 1) mk = ((const uint8_t*) masks_p)[gi] != 0;
        else if (ms == 2) mk = ((const uint16_t*)masks_p)[gi] != 0;
        else              mk = ((const uint32_t*)masks_p)[gi] != 0;
        const float ct1 = ldf(t1_p, gi, fm);
        const float ct2 = ldf(t2_p, gi, fm);
        const float dt = ct2 - ct1;
        const float ax = fmaf(vx, ct1, ox), ay = fmaf(vy, ct1, oy), az = fmaf(vz, ct1, oz);
        const float bx = vx * dt, by = vy * dt, bz = vz * dt;

        float z[DIM];
#pragma unroll
        for (int c = 0; c < DIM; ++c) z[c] = ws[OFF_B0 + c];

        // ---- layer 0: z += x[24] @ W0[24x64] (p-loop runtime to save I$) ----
#pragma unroll 1
        for (int p = 0; p < NPTS; ++p) {
            const float tp = (float)p * (1.0f / 7.0f);
            const float x0 = (fmaf(bx, tp, ax) - mnx) * isx;
            const float x1 = (fmaf(by, tp, ay) - mny) * isy;
            const float x2 = (fmaf(bz, tp, az) - mnz) * isz;
            const float* r0 = ws + OFF_W0 + (3 * p + 0) * 64;
            const float* r1 = ws + OFF_W0 + (3 * p + 1) * 64;
            const float* r2 = ws + OFF_W0 + (3 * p + 2) * 64;
#pragma unroll
            for (int c = 0; c < DIM; ++c)
                z[c] = fmaf(x2, r2[c], fmaf(x1, r1[c], fmaf(x0, r0[c], z[c])));
        }

        // ---- 2 x (relu -> LN -> @Ws + bs); li runtime so code is shared ----
        float y[DIM];
#pragma unroll 1
        for (int li = 0; li < NLAYERS; ++li) {
            float s = 0.f;
#pragma unroll
            for (int c = 0; c < DIM; ++c) { z[c] = fmaxf(z[c], 0.f); s += z[c]; }
            const float mu = s * (1.0f / DIM);
            float v = 0.f;
#pragma unroll
            for (int c = 0; c < DIM; ++c) { float d = z[c] - mu; v = fmaf(d, d, v); }
            const float rs = rsqrtf(fmaf(v, 1.0f / DIM, 1e-5f));
            const float* g  = ws + OFF_G  + li * 64;
            const float* bt = ws + OFF_BT + li * 64;
#pragma unroll
            for (int c = 0; c < DIM; ++c) y[c] = fmaf((z[c] - mu) * rs, g[c], bt[c]);

            const float* bsr = ws + OFF_BS + li * 64;
#pragma unroll
            for (int c = 0; c < DIM; ++c) z[c] = bsr[c];
            const float* wb = ws + OFF_WSM + li * 4096;
#pragma unroll
            for (int k = 0; k < DIM; ++k) {      // FULL unroll: y[k] stays in regs
                const float yk = y[k];
                const float* row = wb + k * 64;
#pragma unroll
                for (int c = 0; c < DIM; ++c) z[c] = fmaf(yk, row[c], z[c]);
            }
        }

        // ---- heads ----
        float cls = bcv, dvv = bdv;
#pragma unroll
        for (int c = 0; c < DIM; ++c) {
            float r = fmaxf(z[c], 0.f);
            cls = fmaf(r, ws[OFF_WC + c], cls);
            dvv = fmaf(r, ws[OFF_WD + c], dvv);
        }
        const float dval = dvv + ct1;
        if (mk && cls > 0.f && dval < dist) dist = dval;
    }

    if (dist == INFV) dist = 0.f;
    const float hit = (dist > 0.f) ? 1.0f : 0.0f;
    if (fm) {
        ((float*)out_p)[ray]         = hit;
        ((float*)out_p)[NRAYS + ray] = dist;
    } else {
        __hip_bfloat16* o = (__hip_bfloat16*)out_p;
        o[ray]         = __float2bfloat16(hit);
        o[NRAYS + ray] = __float2bfloat16(dist);
    }
}

extern "C" void kernel_launch(void* const* d_in, const int* in_sizes, int n_in,
                              void* d_out, int out_size, void* d_ws, size_t ws_size,
                              hipStream_t stream) {
    (void)in_sizes; (void)n_in; (void)ws_size; (void)out_size;
    float* ws = (float*)d_ws;
    conv_k<<<1, 256, 0, stream>>>(
        d_in[6], d_in[7], d_in[2],
        d_in[8], d_in[9], d_in[10], d_in[11],
        d_in[12], d_in[13], d_in[14], d_in[15],
        d_in[16], d_in[17], ws);
    nbvh_main<<<NRAYS / 256, 256, 0, stream>>>(
        d_in[0], d_in[1], d_in[2], d_in[4], d_in[5], ws, d_out);
}